// Round 1
// baseline (2720.776 us; speedup 1.0000x reference)
//
#include <hip/hip_runtime.h>
#include <math.h>

#define U_N 100000
#define I_N 50000
#define DD  64
#define BB  8192
#define TT  30
#define N_EUI 1600000
#define N_EII 800000
#define LN_EPS_ 1e-5f
#define BEH_SCALE_ 0.35f
#define REG_COEF_ 1e-4f

__device__ __forceinline__ float wave_sum64(float v) {
#pragma unroll
  for (int o = 32; o > 0; o >>= 1) v += __shfl_xor(v, o, 64);
  return v;
}

// dst[drows[e]*DD + lane] += vals[e] * src[srows[e]*DD + lane]
__global__ __launch_bounds__(256) void edge_scatter(
    const float* __restrict__ vals, const int* __restrict__ drows,
    const int* __restrict__ srows, const float* __restrict__ src,
    float* __restrict__ dst, int nE) {
  const int lane = threadIdx.x & 63;
  long wid = ((long)blockIdx.x * blockDim.x + threadIdx.x) >> 6;
  long nw = ((long)gridDim.x * blockDim.x) >> 6;
  for (long e = wid; e < nE; e += nw) {
    float v = vals[e];
    int dr = drows[e];
    int sr = srows[e];
    atomicAdd(&dst[(long)dr * DD + lane], v * src[(long)sr * DD + lane]);
  }
}

// buf[r] = relu(buf[r] @ W + bias), in-place (row fits in wave regs)
__global__ __launch_bounds__(256) void matmul_relu_inplace(
    float* __restrict__ buf, const float* __restrict__ W,
    const float* __restrict__ bias, int M) {
  __shared__ float Wl[DD * DD];
  for (int i = threadIdx.x; i < DD * DD; i += blockDim.x) Wl[i] = W[i];
  __syncthreads();
  const int lane = threadIdx.x & 63;
  const float bn = bias[lane];
  long wid = ((long)blockIdx.x * blockDim.x + threadIdx.x) >> 6;
  long nw = ((long)gridDim.x * blockDim.x) >> 6;
  for (long r = wid; r < M; r += nw) {
    float xr = buf[r * DD + lane];
    float acc = bn;
#pragma unroll 16
    for (int k = 0; k < DD; ++k)
      acc = fmaf(__shfl(xr, k, 64), Wl[k * DD + lane], acc);
    buf[r * DD + lane] = fmaxf(acc, 0.f);
  }
}

// seq_x[b,t] = LN( it[seq_items] + 0.35*beh + relu(log1p(dt)*w1+b1)@w2 + b2 )
__global__ __launch_bounds__(256) void seq_encode(
    const float* __restrict__ itf, const float* __restrict__ beh_emb,
    const float* __restrict__ t_w1, const float* __restrict__ t_b1,
    const float* __restrict__ t_w2, const float* __restrict__ t_b2,
    const float* __restrict__ ln_g, const float* __restrict__ ln_b,
    const float* __restrict__ delta, const int* __restrict__ items,
    const int* __restrict__ behs, float* __restrict__ seqx) {
  __shared__ float W2[DD * DD];
  for (int i = threadIdx.x; i < DD * DD; i += blockDim.x) W2[i] = t_w2[i];
  __syncthreads();
  const int lane = threadIdx.x & 63;
  const float w1 = t_w1[lane], b1 = t_b1[lane], b2 = t_b2[lane];
  const float g = ln_g[lane], bo = ln_b[lane];
  long wid = ((long)blockIdx.x * blockDim.x + threadIdx.x) >> 6;
  long nw = ((long)gridDim.x * blockDim.x) >> 6;
  const long NR = (long)BB * TT;
  for (long r = wid; r < NR; r += nw) {
    int it = items[r];
    int bh = behs[r];
    float x = itf[(long)it * DD + lane] + BEH_SCALE_ * beh_emb[bh * DD + lane];
    float tv = log1pf(delta[r]);
    float tmp = fmaxf(fmaf(tv, w1, b1), 0.f);
    float y = b2;
#pragma unroll 16
    for (int k = 0; k < DD; ++k)
      y = fmaf(__shfl(tmp, k, 64), W2[k * DD + lane], y);
    x += y;
    float mu = wave_sum64(x) * (1.f / DD);
    float xc = x - mu;
    float var = wave_sum64(xc * xc) * (1.f / DD);
    float xo = xc * rsqrtf(var + LN_EPS_) * g + bo;
    seqx[r * DD + lane] = xo;
  }
}

// GRU over T steps. Block = 32 batch rows. Register tile per thread:
// 2 rows x 4 dims x {r,z,in,hn}. W_ih+W_hh in LDS (96KB), x/h transposed in LDS.
#define MB 32
#define XSTR 34
__global__ __launch_bounds__(256, 1) void gru_scan(
    const float* __restrict__ seqx, const float* __restrict__ Wih,
    const float* __restrict__ Whh, const float* __restrict__ bih,
    const float* __restrict__ bhh, const int* __restrict__ seq_len,
    float* __restrict__ hfin) {
  __shared__ float sWih[DD * 192];
  __shared__ float sWhh[DD * 192];
  __shared__ float xT[DD * XSTR];
  __shared__ float hT[DD * XSTR];
  const int tid = threadIdx.x;
  for (int i = tid; i < DD * 192; i += 256) {
    sWih[i] = Wih[i];
    sWhh[i] = Whh[i];
  }
  const int ct = tid & 15, rt = tid >> 4;
  const int d0 = ct * 4, r0 = rt * 2;
  const int b0 = blockIdx.x * MB;

  float brz0[4], brz1[4], bn_i[4], bn_h[4];
#pragma unroll
  for (int dd = 0; dd < 4; ++dd) {
    brz0[dd] = bih[d0 + dd] + bhh[d0 + dd];
    brz1[dd] = bih[64 + d0 + dd] + bhh[64 + d0 + dd];
    bn_i[dd] = bih[128 + d0 + dd];
    bn_h[dd] = bhh[128 + d0 + dd];
  }
  const int sl0 = seq_len[b0 + r0], sl1 = seq_len[b0 + r0 + 1];
  float hprev[2][4];
#pragma unroll
  for (int rr = 0; rr < 2; ++rr)
#pragma unroll
    for (int dd = 0; dd < 4; ++dd) hprev[rr][dd] = 0.f;

  const int srow = tid >> 3;          // 0..31
  const int sd0 = (tid & 7) * 8;      // 0..56
  const float* xsrc = seqx + ((long)(b0 + srow) * TT) * DD + sd0;
  __syncthreads();

  for (int t = 0; t < TT; ++t) {
    float4 xa = *(const float4*)(xsrc + t * DD);
    float4 xb = *(const float4*)(xsrc + t * DD + 4);
    xT[(sd0 + 0) * XSTR + srow] = xa.x;
    xT[(sd0 + 1) * XSTR + srow] = xa.y;
    xT[(sd0 + 2) * XSTR + srow] = xa.z;
    xT[(sd0 + 3) * XSTR + srow] = xa.w;
    xT[(sd0 + 4) * XSTR + srow] = xb.x;
    xT[(sd0 + 5) * XSTR + srow] = xb.y;
    xT[(sd0 + 6) * XSTR + srow] = xb.z;
    xT[(sd0 + 7) * XSTR + srow] = xb.w;
#pragma unroll
    for (int dd = 0; dd < 4; ++dd) {
      hT[(d0 + dd) * XSTR + r0] = hprev[0][dd];
      hT[(d0 + dd) * XSTR + r0 + 1] = hprev[1][dd];
    }
    __syncthreads();

    float aR[2][4], aZ[2][4], aN[2][4], aHN[2][4];
#pragma unroll
    for (int dd = 0; dd < 4; ++dd) {
      aR[0][dd] = brz0[dd]; aR[1][dd] = brz0[dd];
      aZ[0][dd] = brz1[dd]; aZ[1][dd] = brz1[dd];
      aN[0][dd] = bn_i[dd]; aN[1][dd] = bn_i[dd];
      aHN[0][dd] = bn_h[dd]; aHN[1][dd] = bn_h[dd];
    }

#pragma unroll 8
    for (int k = 0; k < DD; ++k) {
      float2 xx = *(const float2*)&xT[k * XSTR + r0];
      float2 hh = *(const float2*)&hT[k * XSTR + r0];
      const float* wi = &sWih[k * 192];
      const float* wh = &sWhh[k * 192];
      float wir[4], wiz[4], win[4], whr[4], whz[4], whn[4];
      *(float4*)wir = *(const float4*)(wi + d0);
      *(float4*)wiz = *(const float4*)(wi + 64 + d0);
      *(float4*)win = *(const float4*)(wi + 128 + d0);
      *(float4*)whr = *(const float4*)(wh + d0);
      *(float4*)whz = *(const float4*)(wh + 64 + d0);
      *(float4*)whn = *(const float4*)(wh + 128 + d0);
#pragma unroll
      for (int dd = 0; dd < 4; ++dd) {
        aR[0][dd] = fmaf(xx.x, wir[dd], aR[0][dd]);
        aR[0][dd] = fmaf(hh.x, whr[dd], aR[0][dd]);
        aR[1][dd] = fmaf(xx.y, wir[dd], aR[1][dd]);
        aR[1][dd] = fmaf(hh.y, whr[dd], aR[1][dd]);
        aZ[0][dd] = fmaf(xx.x, wiz[dd], aZ[0][dd]);
        aZ[0][dd] = fmaf(hh.x, whz[dd], aZ[0][dd]);
        aZ[1][dd] = fmaf(xx.y, wiz[dd], aZ[1][dd]);
        aZ[1][dd] = fmaf(hh.y, whz[dd], aZ[1][dd]);
        aN[0][dd] = fmaf(xx.x, win[dd], aN[0][dd]);
        aN[1][dd] = fmaf(xx.y, win[dd], aN[1][dd]);
        aHN[0][dd] = fmaf(hh.x, whn[dd], aHN[0][dd]);
        aHN[1][dd] = fmaf(hh.y, whn[dd], aHN[1][dd]);
      }
    }
#pragma unroll
    for (int rr = 0; rr < 2; ++rr) {
      const int sl = rr ? sl1 : sl0;
      const bool m = t < sl;
#pragma unroll
      for (int dd = 0; dd < 4; ++dd) {
        float rg = 1.f / (1.f + __expf(-aR[rr][dd]));
        float zg = 1.f / (1.f + __expf(-aZ[rr][dd]));
        float ng = tanhf(fmaf(rg, aHN[rr][dd], aN[rr][dd]));
        float hn = (1.f - zg) * ng + zg * hprev[rr][dd];
        hprev[rr][dd] = m ? hn : hprev[rr][dd];
      }
    }
    __syncthreads();
  }
#pragma unroll
  for (int rr = 0; rr < 2; ++rr) {
    float4 o = make_float4(hprev[rr][0], hprev[rr][1], hprev[rr][2], hprev[rr][3]);
    *(float4*)&hfin[(long)(b0 + r0 + rr) * DD + d0] = o;
  }
}

__global__ __launch_bounds__(256) void final_score(
    const float* __restrict__ ufin, const float* __restrict__ itf,
    const float* __restrict__ hfin, const float* __restrict__ ln_g,
    const float* __restrict__ ln_b, const int* __restrict__ user_idx,
    const int* __restrict__ pos_idx, const int* __restrict__ neg_idx,
    const int* __restrict__ pos_beh, float* __restrict__ out) {
  __shared__ float partial[4];
  const int lane = threadIdx.x & 63;
  const int wv = threadIdx.x >> 6;
  const float g = ln_g[lane], bo = ln_b[lane];
  float local = 0.f;
  int wid = blockIdx.x * 4 + wv;
  int nw = gridDim.x * 4;
  for (int r = wid; r < BB; r += nw) {
    float uf = ufin[(long)user_idx[r] * DD + lane] + hfin[(long)r * DD + lane];
    float mu = wave_sum64(uf) * (1.f / DD);
    float xc = uf - mu;
    float var = wave_sum64(xc * xc) * (1.f / DD);
    float un = xc * rsqrtf(var + LN_EPS_) * g + bo;
    float pv = itf[(long)pos_idx[r] * DD + lane];
    float nv = itf[(long)neg_idx[r] * DD + lane];
    float ps = wave_sum64(un * pv);
    float ns = wave_sum64(un * nv);
    float n1 = wave_sum64(un * un);
    float n2 = wave_sum64(pv * pv);
    float n3 = wave_sum64(nv * nv);
    float d = ps - ns;
    float sp = fmaxf(-d, 0.f) + log1pf(__expf(-fabsf(d)));  // softplus(-d)
    int pb = pos_beh[r];
    pb = pb < 0 ? 0 : (pb > 3 ? 3 : pb);
    float bw = pb == 0 ? 1.0f : (pb == 1 ? 1.25f : (pb == 2 ? 1.6f : 2.1f));
    float contrib =
        sp * bw + REG_COEF_ * (sqrtf(n1) + sqrtf(n2) + sqrtf(n3));
    local += contrib;
  }
  if (lane == 0) partial[wv] = local;
  __syncthreads();
  if (threadIdx.x == 0) {
    float s = partial[0] + partial[1] + partial[2] + partial[3];
    atomicAdd(out, s * (1.f / BB));
  }
}

extern "C" void kernel_launch(void* const* d_in, const int* in_sizes, int n_in,
                              void* d_out, int out_size, void* d_ws,
                              size_t ws_size, hipStream_t stream) {
  const float* user_emb = (const float*)d_in[0];
  const float* item_emb = (const float*)d_in[1];
  const float* beh_emb = (const float*)d_in[2];
  const float* t_w1 = (const float*)d_in[3];
  const float* t_b1 = (const float*)d_in[4];
  const float* t_w2 = (const float*)d_in[5];
  const float* t_b2 = (const float*)d_in[6];
  const float* gru_w_ih = (const float*)d_in[7];
  const float* gru_w_hh = (const float*)d_in[8];
  const float* gru_b_ih = (const float*)d_in[9];
  const float* gru_b_hh = (const float*)d_in[10];
  const float* gnn_user_w = (const float*)d_in[11];
  const float* gnn_user_b = (const float*)d_in[12];
  const float* gnn_item_w = (const float*)d_in[13];
  const float* gnn_item_b = (const float*)d_in[14];
  const float* ln_g = (const float*)d_in[15];
  const float* ln_b = (const float*)d_in[16];
  const float* ui_vals = (const float*)d_in[17];
  const float* adj_vals = (const float*)d_in[18];
  const float* seq_delta = (const float*)d_in[19];
  const int* ui_rows = (const int*)d_in[20];
  const int* ui_cols = (const int*)d_in[21];
  const int* adj_rows = (const int*)d_in[22];
  const int* adj_cols = (const int*)d_in[23];
  const int* seq_items = (const int*)d_in[24];
  const int* seq_behaviors = (const int*)d_in[25];
  const int* seq_len = (const int*)d_in[26];
  const int* user_idx = (const int*)d_in[27];
  const int* pos_item_idx = (const int*)d_in[28];
  const int* neg_item_idx = (const int*)d_in[29];
  const int* pos_behavior = (const int*)d_in[30];

  float* ws = (float*)d_ws;
  float* u_a = ws;
  float* u_b = u_a + (long)U_N * DD;
  float* it_a = u_b + (long)U_N * DD;
  float* it_b = it_a + (long)I_N * DD;
  float* seqx = it_b + (long)I_N * DD;
  float* hfin = seqx + (long)BB * TT * DD;

  hipMemsetAsync(d_out, 0, (size_t)out_size * sizeof(float), stream);

  // ---- GNN layer 0 (cur = inputs, acc = *_a) ----
  hipMemcpyAsync(u_a, user_emb, (size_t)U_N * DD * sizeof(float),
                 hipMemcpyDeviceToDevice, stream);
  hipMemcpyAsync(it_a, item_emb, (size_t)I_N * DD * sizeof(float),
                 hipMemcpyDeviceToDevice, stream);
  edge_scatter<<<4096, 256, 0, stream>>>(ui_vals, ui_rows, ui_cols, item_emb,
                                         u_a, N_EUI);
  edge_scatter<<<4096, 256, 0, stream>>>(adj_vals, adj_rows, adj_cols, item_emb,
                                         it_a, N_EII);
  edge_scatter<<<4096, 256, 0, stream>>>(ui_vals, ui_cols, ui_rows, user_emb,
                                         it_a, N_EUI);
  matmul_relu_inplace<<<2048, 256, 0, stream>>>(u_a, gnn_user_w, gnn_user_b,
                                                U_N);
  matmul_relu_inplace<<<2048, 256, 0, stream>>>(it_a, gnn_item_w, gnn_item_b,
                                                I_N);

  // ---- GNN layer 1 (cur = *_a, acc = *_b) ----
  hipMemcpyAsync(u_b, u_a, (size_t)U_N * DD * sizeof(float),
                 hipMemcpyDeviceToDevice, stream);
  hipMemcpyAsync(it_b, it_a, (size_t)I_N * DD * sizeof(float),
                 hipMemcpyDeviceToDevice, stream);
  edge_scatter<<<4096, 256, 0, stream>>>(ui_vals, ui_rows, ui_cols, it_a, u_b,
                                         N_EUI);
  edge_scatter<<<4096, 256, 0, stream>>>(adj_vals, adj_rows, adj_cols, it_a,
                                         it_b, N_EII);
  edge_scatter<<<4096, 256, 0, stream>>>(ui_vals, ui_cols, ui_rows, u_a, it_b,
                                         N_EUI);
  matmul_relu_inplace<<<2048, 256, 0, stream>>>(u_b, gnn_user_w + DD * DD,
                                                gnn_user_b + DD, U_N);
  matmul_relu_inplace<<<2048, 256, 0, stream>>>(it_b, gnn_item_w + DD * DD,
                                                gnn_item_b + DD, I_N);

  // ---- sequence encoding ----
  seq_encode<<<2048, 256, 0, stream>>>(it_b, beh_emb, t_w1, t_b1, t_w2, t_b2,
                                       ln_g, ln_b, seq_delta, seq_items,
                                       seq_behaviors, seqx);

  // ---- GRU scan ----
  gru_scan<<<BB / MB, 256, 0, stream>>>(seqx, gru_w_ih, gru_w_hh, gru_b_ih,
                                        gru_b_hh, seq_len, hfin);

  // ---- final scoring + reduction ----
  final_score<<<256, 256, 0, stream>>>(u_b, it_b, hfin, ln_g, ln_b, user_idx,
                                       pos_item_idx, neg_item_idx, pos_behavior,
                                       (float*)d_out);
}

// Round 2
// 2331.861 us; speedup vs baseline: 1.1668x; 1.1668x over previous
//
#include <hip/hip_runtime.h>
#include <math.h>

#define U_N 100000
#define I_N 50000
#define DD  64
#define BB  8192
#define TT  30
#define N_EUI 1600000
#define N_EII 800000
#define LN_EPS_ 1e-5f
#define BEH_SCALE_ 0.35f
#define REG_COEF_ 1e-4f

__device__ __forceinline__ float wave_sum64(float v) {
#pragma unroll
  for (int o = 32; o > 0; o >>= 1) v += __shfl_xor(v, o, 64);
  return v;
}

// ---------------- CSR build ----------------

__global__ __launch_bounds__(256) void hist_kernel(
    const int* __restrict__ rows, int nE, int* __restrict__ cnt) {
  for (long e = (long)blockIdx.x * blockDim.x + threadIdx.x; e < nE;
       e += (long)gridDim.x * blockDim.x)
    atomicAdd(&cnt[rows[e]], 1);
}

// single-block exclusive scan; cnt may alias cursor (read-before-write per elem)
__global__ __launch_bounds__(1024) void ex_scan(
    const int* __restrict__ cnt, int n, int* __restrict__ offs,
    int* __restrict__ cursor) {
  __shared__ int part[1024];
  const int tid = threadIdx.x;
  const int chunk = (n + 1023) / 1024;
  const int lo = tid * chunk;
  const int hi = min(lo + chunk, n);
  int s = 0;
  for (int i = lo; i < hi; ++i) s += cnt[i];
  part[tid] = s;
  __syncthreads();
  for (int off = 1; off < 1024; off <<= 1) {
    int v = part[tid];
    int add = (tid >= off) ? part[tid - off] : 0;
    __syncthreads();
    part[tid] = v + add;
    __syncthreads();
  }
  int base = (tid == 0) ? 0 : part[tid - 1];
  for (int i = lo; i < hi; ++i) {
    int c = cnt[i];        // read BEFORE writing (cnt aliases cursor)
    offs[i] = base;
    cursor[i] = base;
    base += c;
  }
  if (tid == 0) offs[n] = part[1023];
}

__global__ __launch_bounds__(256) void csr_fill(
    const int* __restrict__ drows, const int* __restrict__ srows,
    const float* __restrict__ vals, int nE, int* __restrict__ cursor,
    int2* __restrict__ pairs) {
  for (long e = (long)blockIdx.x * blockDim.x + threadIdx.x; e < nE;
       e += (long)gridDim.x * blockDim.x) {
    int d = drows[e];
    int pos = atomicAdd(&cursor[d], 1);
    pairs[pos] = make_int2(srows[e], __float_as_int(vals[e]));
  }
}

// ---------------- fused GNN layers (gather + matmul + relu) ----------------

// out[r] = relu((cur_u[r] + sum_j val*src_it[src]) @ W + b)
__global__ __launch_bounds__(256) void gnn_user_layer(
    const float* __restrict__ cur_u, const float* __restrict__ src_it,
    const int* __restrict__ offs, const int2* __restrict__ pairs,
    const float* __restrict__ W, const float* __restrict__ bias,
    float* __restrict__ out) {
  __shared__ float Wl[DD * DD];
  for (int i = threadIdx.x; i < DD * DD; i += blockDim.x) Wl[i] = W[i];
  __syncthreads();
  const int lane = threadIdx.x & 63;
  const float bn = bias[lane];
  long wid = ((long)blockIdx.x * blockDim.x + threadIdx.x) >> 6;
  long nw = ((long)gridDim.x * blockDim.x) >> 6;
  for (long r = wid; r < U_N; r += nw) {
    float acc = cur_u[r * DD + lane];
    int j1 = offs[r + 1];
    for (int j = offs[r]; j < j1; ++j) {
      int2 p = pairs[j];
      acc = fmaf(__int_as_float(p.y), src_it[(long)p.x * DD + lane], acc);
    }
    float y = bn;
#pragma unroll 16
    for (int k = 0; k < DD; ++k)
      y = fmaf(__shfl(acc, k, 64), Wl[k * DD + lane], y);
    out[r * DD + lane] = fmaxf(y, 0.f);
  }
}

// out[r] = relu((cur_it[r] + sumA val*cur_it[src] + sumB val*cur_u[src]) @ W + b)
__global__ __launch_bounds__(256) void gnn_item_layer(
    const float* __restrict__ cur_it, const float* __restrict__ cur_u,
    const int* __restrict__ offsA, const int2* __restrict__ pairsA,
    const int* __restrict__ offsB, const int2* __restrict__ pairsB,
    const float* __restrict__ W, const float* __restrict__ bias,
    float* __restrict__ out) {
  __shared__ float Wl[DD * DD];
  for (int i = threadIdx.x; i < DD * DD; i += blockDim.x) Wl[i] = W[i];
  __syncthreads();
  const int lane = threadIdx.x & 63;
  const float bn = bias[lane];
  long wid = ((long)blockIdx.x * blockDim.x + threadIdx.x) >> 6;
  long nw = ((long)gridDim.x * blockDim.x) >> 6;
  for (long r = wid; r < I_N; r += nw) {
    float acc = cur_it[r * DD + lane];
    int j1 = offsA[r + 1];
    for (int j = offsA[r]; j < j1; ++j) {
      int2 p = pairsA[j];
      acc = fmaf(__int_as_float(p.y), cur_it[(long)p.x * DD + lane], acc);
    }
    int j3 = offsB[r + 1];
    for (int j = offsB[r]; j < j3; ++j) {
      int2 p = pairsB[j];
      acc = fmaf(__int_as_float(p.y), cur_u[(long)p.x * DD + lane], acc);
    }
    float y = bn;
#pragma unroll 16
    for (int k = 0; k < DD; ++k)
      y = fmaf(__shfl(acc, k, 64), Wl[k * DD + lane], y);
    out[r * DD + lane] = fmaxf(y, 0.f);
  }
}

// ---------------- sequence encode ----------------

__global__ __launch_bounds__(256) void seq_encode(
    const float* __restrict__ itf, const float* __restrict__ beh_emb,
    const float* __restrict__ t_w1, const float* __restrict__ t_b1,
    const float* __restrict__ t_w2, const float* __restrict__ t_b2,
    const float* __restrict__ ln_g, const float* __restrict__ ln_b,
    const float* __restrict__ delta, const int* __restrict__ items,
    const int* __restrict__ behs, float* __restrict__ seqx) {
  __shared__ float W2[DD * DD];
  for (int i = threadIdx.x; i < DD * DD; i += blockDim.x) W2[i] = t_w2[i];
  __syncthreads();
  const int lane = threadIdx.x & 63;
  const float w1 = t_w1[lane], b1 = t_b1[lane], b2 = t_b2[lane];
  const float g = ln_g[lane], bo = ln_b[lane];
  long wid = ((long)blockIdx.x * blockDim.x + threadIdx.x) >> 6;
  long nw = ((long)gridDim.x * blockDim.x) >> 6;
  const long NR = (long)BB * TT;
  for (long r = wid; r < NR; r += nw) {
    int it = items[r];
    int bh = behs[r];
    float x = itf[(long)it * DD + lane] + BEH_SCALE_ * beh_emb[bh * DD + lane];
    float tv = log1pf(delta[r]);
    float tmp = fmaxf(fmaf(tv, w1, b1), 0.f);
    float y = b2;
#pragma unroll 16
    for (int k = 0; k < DD; ++k)
      y = fmaf(__shfl(tmp, k, 64), W2[k * DD + lane], y);
    x += y;
    float mu = wave_sum64(x) * (1.f / DD);
    float xc = x - mu;
    float var = wave_sum64(xc * xc) * (1.f / DD);
    float xo = xc * rsqrtf(var + LN_EPS_) * g + bo;
    seqx[r * DD + lane] = xo;
  }
}

// ---------------- GRU ----------------
#define MB 32
#define XSTR 34
__global__ __launch_bounds__(256, 1) void gru_scan(
    const float* __restrict__ seqx, const float* __restrict__ Wih,
    const float* __restrict__ Whh, const float* __restrict__ bih,
    const float* __restrict__ bhh, const int* __restrict__ seq_len,
    float* __restrict__ hfin) {
  __shared__ float sWih[DD * 192];
  __shared__ float sWhh[DD * 192];
  __shared__ float xT[DD * XSTR];
  __shared__ float hT[DD * XSTR];
  const int tid = threadIdx.x;
  for (int i = tid; i < DD * 192; i += 256) {
    sWih[i] = Wih[i];
    sWhh[i] = Whh[i];
  }
  const int ct = tid & 15, rt = tid >> 4;
  const int d0 = ct * 4, r0 = rt * 2;
  const int b0 = blockIdx.x * MB;

  float brz0[4], brz1[4], bn_i[4], bn_h[4];
#pragma unroll
  for (int dd = 0; dd < 4; ++dd) {
    brz0[dd] = bih[d0 + dd] + bhh[d0 + dd];
    brz1[dd] = bih[64 + d0 + dd] + bhh[64 + d0 + dd];
    bn_i[dd] = bih[128 + d0 + dd];
    bn_h[dd] = bhh[128 + d0 + dd];
  }
  const int sl0 = seq_len[b0 + r0], sl1 = seq_len[b0 + r0 + 1];
  float hprev[2][4];
#pragma unroll
  for (int rr = 0; rr < 2; ++rr)
#pragma unroll
    for (int dd = 0; dd < 4; ++dd) hprev[rr][dd] = 0.f;

  const int srow = tid >> 3;
  const int sd0 = (tid & 7) * 8;
  const float* xsrc = seqx + ((long)(b0 + srow) * TT) * DD + sd0;
  __syncthreads();

  for (int t = 0; t < TT; ++t) {
    float4 xa = *(const float4*)(xsrc + t * DD);
    float4 xb = *(const float4*)(xsrc + t * DD + 4);
    xT[(sd0 + 0) * XSTR + srow] = xa.x;
    xT[(sd0 + 1) * XSTR + srow] = xa.y;
    xT[(sd0 + 2) * XSTR + srow] = xa.z;
    xT[(sd0 + 3) * XSTR + srow] = xa.w;
    xT[(sd0 + 4) * XSTR + srow] = xb.x;
    xT[(sd0 + 5) * XSTR + srow] = xb.y;
    xT[(sd0 + 6) * XSTR + srow] = xb.z;
    xT[(sd0 + 7) * XSTR + srow] = xb.w;
#pragma unroll
    for (int dd = 0; dd < 4; ++dd) {
      hT[(d0 + dd) * XSTR + r0] = hprev[0][dd];
      hT[(d0 + dd) * XSTR + r0 + 1] = hprev[1][dd];
    }
    __syncthreads();

    float aR[2][4], aZ[2][4], aN[2][4], aHN[2][4];
#pragma unroll
    for (int dd = 0; dd < 4; ++dd) {
      aR[0][dd] = brz0[dd]; aR[1][dd] = brz0[dd];
      aZ[0][dd] = brz1[dd]; aZ[1][dd] = brz1[dd];
      aN[0][dd] = bn_i[dd]; aN[1][dd] = bn_i[dd];
      aHN[0][dd] = bn_h[dd]; aHN[1][dd] = bn_h[dd];
    }

#pragma unroll 8
    for (int k = 0; k < DD; ++k) {
      float2 xx = *(const float2*)&xT[k * XSTR + r0];
      float2 hh = *(const float2*)&hT[k * XSTR + r0];
      const float* wi = &sWih[k * 192];
      const float* wh = &sWhh[k * 192];
      float wir[4], wiz[4], win[4], whr[4], whz[4], whn[4];
      *(float4*)wir = *(const float4*)(wi + d0);
      *(float4*)wiz = *(const float4*)(wi + 64 + d0);
      *(float4*)win = *(const float4*)(wi + 128 + d0);
      *(float4*)whr = *(const float4*)(wh + d0);
      *(float4*)whz = *(const float4*)(wh + 64 + d0);
      *(float4*)whn = *(const float4*)(wh + 128 + d0);
#pragma unroll
      for (int dd = 0; dd < 4; ++dd) {
        aR[0][dd] = fmaf(xx.x, wir[dd], aR[0][dd]);
        aR[0][dd] = fmaf(hh.x, whr[dd], aR[0][dd]);
        aR[1][dd] = fmaf(xx.y, wir[dd], aR[1][dd]);
        aR[1][dd] = fmaf(hh.y, whr[dd], aR[1][dd]);
        aZ[0][dd] = fmaf(xx.x, wiz[dd], aZ[0][dd]);
        aZ[0][dd] = fmaf(hh.x, whz[dd], aZ[0][dd]);
        aZ[1][dd] = fmaf(xx.y, wiz[dd], aZ[1][dd]);
        aZ[1][dd] = fmaf(hh.y, whz[dd], aZ[1][dd]);
        aN[0][dd] = fmaf(xx.x, win[dd], aN[0][dd]);
        aN[1][dd] = fmaf(xx.y, win[dd], aN[1][dd]);
        aHN[0][dd] = fmaf(hh.x, whn[dd], aHN[0][dd]);
        aHN[1][dd] = fmaf(hh.y, whn[dd], aHN[1][dd]);
      }
    }
#pragma unroll
    for (int rr = 0; rr < 2; ++rr) {
      const int sl = rr ? sl1 : sl0;
      const bool m = t < sl;
#pragma unroll
      for (int dd = 0; dd < 4; ++dd) {
        float rg = 1.f / (1.f + __expf(-aR[rr][dd]));
        float zg = 1.f / (1.f + __expf(-aZ[rr][dd]));
        float ng = tanhf(fmaf(rg, aHN[rr][dd], aN[rr][dd]));
        float hn = (1.f - zg) * ng + zg * hprev[rr][dd];
        hprev[rr][dd] = m ? hn : hprev[rr][dd];
      }
    }
    __syncthreads();
  }
#pragma unroll
  for (int rr = 0; rr < 2; ++rr) {
    float4 o = make_float4(hprev[rr][0], hprev[rr][1], hprev[rr][2], hprev[rr][3]);
    *(float4*)&hfin[(long)(b0 + r0 + rr) * DD + d0] = o;
  }
}

// ---------------- final scoring ----------------

__global__ __launch_bounds__(256) void final_score(
    const float* __restrict__ ufin, const float* __restrict__ itf,
    const float* __restrict__ hfin, const float* __restrict__ ln_g,
    const float* __restrict__ ln_b, const int* __restrict__ user_idx,
    const int* __restrict__ pos_idx, const int* __restrict__ neg_idx,
    const int* __restrict__ pos_beh, float* __restrict__ out) {
  __shared__ float partial[4];
  const int lane = threadIdx.x & 63;
  const int wv = threadIdx.x >> 6;
  const float g = ln_g[lane], bo = ln_b[lane];
  float local = 0.f;
  int wid = blockIdx.x * 4 + wv;
  int nw = gridDim.x * 4;
  for (int r = wid; r < BB; r += nw) {
    float uf = ufin[(long)user_idx[r] * DD + lane] + hfin[(long)r * DD + lane];
    float mu = wave_sum64(uf) * (1.f / DD);
    float xc = uf - mu;
    float var = wave_sum64(xc * xc) * (1.f / DD);
    float un = xc * rsqrtf(var + LN_EPS_) * g + bo;
    float pv = itf[(long)pos_idx[r] * DD + lane];
    float nv = itf[(long)neg_idx[r] * DD + lane];
    float ps = wave_sum64(un * pv);
    float ns = wave_sum64(un * nv);
    float n1 = wave_sum64(un * un);
    float n2 = wave_sum64(pv * pv);
    float n3 = wave_sum64(nv * nv);
    float d = ps - ns;
    float sp = fmaxf(-d, 0.f) + log1pf(__expf(-fabsf(d)));
    int pb = pos_beh[r];
    pb = pb < 0 ? 0 : (pb > 3 ? 3 : pb);
    float bw = pb == 0 ? 1.0f : (pb == 1 ? 1.25f : (pb == 2 ? 1.6f : 2.1f));
    local += sp * bw + REG_COEF_ * (sqrtf(n1) + sqrtf(n2) + sqrtf(n3));
  }
  if (lane == 0) partial[wv] = local;
  __syncthreads();
  if (threadIdx.x == 0) {
    float s = partial[0] + partial[1] + partial[2] + partial[3];
    atomicAdd(out, s * (1.f / BB));
  }
}

extern "C" void kernel_launch(void* const* d_in, const int* in_sizes, int n_in,
                              void* d_out, int out_size, void* d_ws,
                              size_t ws_size, hipStream_t stream) {
  const float* user_emb = (const float*)d_in[0];
  const float* item_emb = (const float*)d_in[1];
  const float* beh_emb = (const float*)d_in[2];
  const float* t_w1 = (const float*)d_in[3];
  const float* t_b1 = (const float*)d_in[4];
  const float* t_w2 = (const float*)d_in[5];
  const float* t_b2 = (const float*)d_in[6];
  const float* gru_w_ih = (const float*)d_in[7];
  const float* gru_w_hh = (const float*)d_in[8];
  const float* gru_b_ih = (const float*)d_in[9];
  const float* gru_b_hh = (const float*)d_in[10];
  const float* gnn_user_w = (const float*)d_in[11];
  const float* gnn_user_b = (const float*)d_in[12];
  const float* gnn_item_w = (const float*)d_in[13];
  const float* gnn_item_b = (const float*)d_in[14];
  const float* ln_g = (const float*)d_in[15];
  const float* ln_b = (const float*)d_in[16];
  const float* ui_vals = (const float*)d_in[17];
  const float* adj_vals = (const float*)d_in[18];
  const float* seq_delta = (const float*)d_in[19];
  const int* ui_rows = (const int*)d_in[20];
  const int* ui_cols = (const int*)d_in[21];
  const int* adj_rows = (const int*)d_in[22];
  const int* adj_cols = (const int*)d_in[23];
  const int* seq_items = (const int*)d_in[24];
  const int* seq_behaviors = (const int*)d_in[25];
  const int* seq_len = (const int*)d_in[26];
  const int* user_idx = (const int*)d_in[27];
  const int* pos_item_idx = (const int*)d_in[28];
  const int* neg_item_idx = (const int*)d_in[29];
  const int* pos_behavior = (const int*)d_in[30];

  float* ws = (float*)d_ws;
  float* u_a = ws;                                  // 6,400,000
  float* u_b = u_a + (long)U_N * DD;                // 6,400,000
  float* it_a = u_b + (long)U_N * DD;               // 3,200,000
  float* it_b = it_a + (long)I_N * DD;              // 3,200,000
  float* seqx = it_b + (long)I_N * DD;              // 15,728,640
  float* hfin = seqx + (long)BB * TT * DD;          // 524,288
  float* end_f = hfin + (long)BB * DD;

  // CSR region (8B aligned: end_f is at an even float offset)
  int2* pairs_ui_row = (int2*)end_f;                // 1.6M int2
  int2* pairs_ui_col = pairs_ui_row + N_EUI;        // 1.6M int2
  int2* pairs_adj = pairs_ui_col + N_EUI;           // 0.8M int2
  int* offs_ui_row = (int*)(pairs_adj + N_EII);     // U+1
  int* offs_ui_col = offs_ui_row + (U_N + 1);       // I+1
  int* offs_adj = offs_ui_col + (I_N + 1);          // I+1
  int* cur_ui_row = offs_adj + (I_N + 1);           // U
  int* cur_ui_col = cur_ui_row + U_N;               // I
  int* cur_adj = cur_ui_col + I_N;                  // I

  hipMemsetAsync(d_out, 0, (size_t)out_size * sizeof(float), stream);
  // zero the three cursor/count arrays in one shot (contiguous)
  hipMemsetAsync(cur_ui_row, 0, (size_t)(U_N + I_N + I_N) * sizeof(int),
                 stream);

  // ---- CSR build (counts into cursor, scan aliased, fill) ----
  hist_kernel<<<2048, 256, 0, stream>>>(ui_rows, N_EUI, cur_ui_row);
  hist_kernel<<<2048, 256, 0, stream>>>(ui_cols, N_EUI, cur_ui_col);
  hist_kernel<<<1024, 256, 0, stream>>>(adj_rows, N_EII, cur_adj);
  ex_scan<<<1, 1024, 0, stream>>>(cur_ui_row, U_N, offs_ui_row, cur_ui_row);
  ex_scan<<<1, 1024, 0, stream>>>(cur_ui_col, I_N, offs_ui_col, cur_ui_col);
  ex_scan<<<1, 1024, 0, stream>>>(cur_adj, I_N, offs_adj, cur_adj);
  csr_fill<<<2048, 256, 0, stream>>>(ui_rows, ui_cols, ui_vals, N_EUI,
                                     cur_ui_row, pairs_ui_row);
  csr_fill<<<2048, 256, 0, stream>>>(ui_cols, ui_rows, ui_vals, N_EUI,
                                     cur_ui_col, pairs_ui_col);
  csr_fill<<<1024, 256, 0, stream>>>(adj_rows, adj_cols, adj_vals, N_EII,
                                     cur_adj, pairs_adj);

  // ---- GNN layer 0 ----
  gnn_user_layer<<<2048, 256, 0, stream>>>(user_emb, item_emb, offs_ui_row,
                                           pairs_ui_row, gnn_user_w,
                                           gnn_user_b, u_a);
  gnn_item_layer<<<2048, 256, 0, stream>>>(item_emb, user_emb, offs_adj,
                                           pairs_adj, offs_ui_col,
                                           pairs_ui_col, gnn_item_w,
                                           gnn_item_b, it_a);
  // ---- GNN layer 1 ----
  gnn_user_layer<<<2048, 256, 0, stream>>>(u_a, it_a, offs_ui_row, pairs_ui_row,
                                           gnn_user_w + DD * DD,
                                           gnn_user_b + DD, u_b);
  gnn_item_layer<<<2048, 256, 0, stream>>>(it_a, u_a, offs_adj, pairs_adj,
                                           offs_ui_col, pairs_ui_col,
                                           gnn_item_w + DD * DD,
                                           gnn_item_b + DD, it_b);

  // ---- sequence encoding ----
  seq_encode<<<2048, 256, 0, stream>>>(it_b, beh_emb, t_w1, t_b1, t_w2, t_b2,
                                       ln_g, ln_b, seq_delta, seq_items,
                                       seq_behaviors, seqx);

  // ---- GRU scan ----
  gru_scan<<<BB / MB, 256, 0, stream>>>(seqx, gru_w_ih, gru_w_hh, gru_b_ih,
                                        gru_b_hh, seq_len, hfin);

  // ---- final scoring + reduction ----
  final_score<<<256, 256, 0, stream>>>(u_b, it_b, hfin, ln_g, ln_b, user_idx,
                                       pos_item_idx, neg_item_idx, pos_behavior,
                                       (float*)d_out);
}